// Round 7
// baseline (42.838 us; speedup 1.0000x reference)
//
#include <hip/hip_runtime.h>

#define B_ 2
#define N_ 28
#define D_ 128
#define H_ 8
#define DK_ 16
#define R_ (B_ * N_ * N_)   // 1568
#define ROWS_PER_BLK 8      // 196 row-tiles of 8

// ws layout (floats):
//   [0 .. 4*R_*D_)                 : lk, rk, lv, rv   (proj outputs)
//   [4*R_*D_ .. 5*R_*D_)           : xbuf (pre-Wout x)
//   [WT_OFF .. WT_OFF + 5*D_*D_)   : Wt for {Wlk,Wrk,Wlv,Wrv,Wout}
#define WT_OFF (2u << 20)  // 2M floats = 8 MB in; clear of the above (~4 MB)

// ---------------------------------------------------------------------------
// Kernel 0: transpose all five W matrices: Wt[k][c] = W[c][k].
// Grid (16 tiles, 5 matrices), block (32,8). LDS 32x33 padded tile.
// ---------------------------------------------------------------------------
__global__ __launch_bounds__(256) void transposeW_kernel(
    const float* __restrict__ Wlk, const float* __restrict__ Wrk,
    const float* __restrict__ Wlv, const float* __restrict__ Wrv,
    const float* __restrict__ Wout, float* __restrict__ wt) {
  const int wi = blockIdx.y;
  const float* src = (wi == 0) ? Wlk
                   : (wi == 1) ? Wrk
                   : (wi == 2) ? Wlv
                   : (wi == 3) ? Wrv : Wout;
  float* dst = wt + (size_t)wi * D_ * D_;

  const int tr = blockIdx.x >> 2;   // tile row 0..3   (rows of W)
  const int tc = blockIdx.x & 3;    // tile col 0..3   (cols of W)
  const int r0 = tr * 32, c0 = tc * 32;
  const int tx = threadIdx.x;       // 0..31
  const int ty = threadIdx.y;       // 0..7

  __shared__ float t[32][33];
#pragma unroll
  for (int i = 0; i < 4; ++i)
    t[ty + 8 * i][tx] = src[(size_t)(r0 + ty + 8 * i) * D_ + c0 + tx];
  __syncthreads();
#pragma unroll
  for (int i = 0; i < 4; ++i)
    dst[(size_t)(c0 + ty + 8 * i) * D_ + r0 + tx] = t[tx][ty + 8 * i];
}

// ---------------------------------------------------------------------------
// Kernel 1: four projections with transposed weights.
// y[r][c] = sum_k X[r][k] * Wt[k][c].
// Block: 256 thr = (rr = tid>>5: row 0..7, cq = tid&31: col-quad), 8 rows/blk.
// Wt row reads are contiguous 512B per wave-inst; X[r][k] broadcast from LDS.
// ---------------------------------------------------------------------------
__global__ __launch_bounds__(256) void proj4t_kernel(
    const float* __restrict__ key, const float* __restrict__ value,
    const float* __restrict__ wt, float* __restrict__ ws) {
  const int p = blockIdx.y;
  const float* X = (p < 2) ? key : value;
  const float* Wt = wt + (size_t)p * D_ * D_;
  float* Y = ws + (size_t)p * R_ * D_;

  const int r0 = blockIdx.x * ROWS_PER_BLK;
  const int tid = threadIdx.x;
  const int rr = tid >> 5;   // row within tile
  const int cq = tid & 31;   // column quad (cols 4cq..4cq+3)

  __shared__ __align__(16) float xs[ROWS_PER_BLK][D_];
  // cooperative load of the 8x128 X tile (each thread one float4)
  reinterpret_cast<float4*>(xs[rr])[cq] =
      reinterpret_cast<const float4*>(X + (size_t)(r0 + rr) * D_)[cq];
  __syncthreads();

  const float* xrow = xs[rr];
  float4 acc = {0.f, 0.f, 0.f, 0.f};
#pragma unroll 8
  for (int k = 0; k < D_; ++k) {
    const float4 wv = reinterpret_cast<const float4*>(Wt + (size_t)k * D_)[cq];
    const float xk = xrow[k];
    acc.x += xk * wv.x;
    acc.y += xk * wv.y;
    acc.z += xk * wv.z;
    acc.w += xk * wv.w;
  }
  reinterpret_cast<float4*>(Y + (size_t)(r0 + rr) * D_)[cq] = acc;
}

// ---------------------------------------------------------------------------
// Kernel 2: attention (R1's proven v1 body, unchanged).
// Block = one (b,x,y) task, 128 threads = (h = tid>>4, d = tid&15).
// ---------------------------------------------------------------------------
__global__ __launch_bounds__(128) void attn_kernel(
    const float* __restrict__ ws, const int* __restrict__ mask,
    float* __restrict__ xout) {
  const float* lk = ws;
  const float* rk = ws + (size_t)1 * R_ * D_;
  const float* lv = ws + (size_t)2 * R_ * D_;
  const float* rv = ws + (size_t)3 * R_ * D_;

  const int bxy = blockIdx.x;   // (b*28 + x)*28 + y
  const int y = bxy % N_;
  const int bx = bxy / N_;      // b*28 + x
  const int b = bx / N_;
  const int tid = threadIdx.x;

  const int rowL = bx * N_;          // + a      (rows of lk / lv)
  const int rowR = b * N_ * N_ + y;  // + a*N_   (rows of rk / rv)

  float s[N_];
#pragma unroll
  for (int a = 0; a < N_; ++a) {
    float pr = lk[(size_t)(rowL + a) * D_ + tid] *
               rk[(size_t)(rowR + a * N_) * D_ + tid];
    pr += __shfl_xor(pr, 1);
    pr += __shfl_xor(pr, 2);
    pr += __shfl_xor(pr, 4);
    pr += __shfl_xor(pr, 8);
    s[a] = pr * 0.25f;  // / sqrt(DK) = / 4
  }

  const int* mrow = mask + (size_t)rowL * N_ + y;  // mask[(rowL+a)*28 + y]
#pragma unroll
  for (int a = 0; a < N_; ++a)
    if (mrow[(size_t)a * N_] != 0) s[a] = -1e9f;

  float mx = -3.0e38f;
#pragma unroll
  for (int a = 0; a < N_; ++a) mx = fmaxf(mx, s[a]);
  float den = 0.f;
#pragma unroll
  for (int a = 0; a < N_; ++a) {
    s[a] = __expf(s[a] - mx);
    den += s[a];
  }
  const float inv = 1.0f / den;

  float xv = 0.f;
#pragma unroll
  for (int a = 0; a < N_; ++a) {
    xv += s[a] * lv[(size_t)(rowL + a) * D_ + tid] *
          rv[(size_t)(rowR + a * N_) * D_ + tid];
  }
  xout[(size_t)bxy * D_ + tid] = xv * inv;
}

// ---------------------------------------------------------------------------
// Kernel 3: out = x @ Wout^T with transposed Wout (same structure as proj4t).
// ---------------------------------------------------------------------------
__global__ __launch_bounds__(256) void gemm_outt_kernel(
    const float* __restrict__ X, const float* __restrict__ wtOut,
    float* __restrict__ Y) {
  const int r0 = blockIdx.x * ROWS_PER_BLK;
  const int tid = threadIdx.x;
  const int rr = tid >> 5;
  const int cq = tid & 31;

  __shared__ __align__(16) float xs[ROWS_PER_BLK][D_];
  reinterpret_cast<float4*>(xs[rr])[cq] =
      reinterpret_cast<const float4*>(X + (size_t)(r0 + rr) * D_)[cq];
  __syncthreads();

  const float* xrow = xs[rr];
  float4 acc = {0.f, 0.f, 0.f, 0.f};
#pragma unroll 8
  for (int k = 0; k < D_; ++k) {
    const float4 wv =
        reinterpret_cast<const float4*>(wtOut + (size_t)k * D_)[cq];
    const float xk = xrow[k];
    acc.x += xk * wv.x;
    acc.y += xk * wv.y;
    acc.z += xk * wv.z;
    acc.w += xk * wv.w;
  }
  reinterpret_cast<float4*>(Y + (size_t)(r0 + rr) * D_)[cq] = acc;
}

extern "C" void kernel_launch(void* const* d_in, const int* in_sizes, int n_in,
                              void* d_out, int out_size, void* d_ws,
                              size_t ws_size, hipStream_t stream) {
  // 0 query (unused), 1 key, 2 value, 3 mask, 4 Wlk, 5 Wrk, 6 Wlv, 7 Wrv,
  // 8 Wq (unused), 9 Wout
  const float* key = (const float*)d_in[1];
  const float* value = (const float*)d_in[2];
  const int* mask = (const int*)d_in[3];
  const float* Wlk = (const float*)d_in[4];
  const float* Wrk = (const float*)d_in[5];
  const float* Wlv = (const float*)d_in[6];
  const float* Wrv = (const float*)d_in[7];
  const float* Wout = (const float*)d_in[9];
  float* out = (float*)d_out;
  float* ws = (float*)d_ws;

  float* xbuf = ws + (size_t)4 * R_ * D_;   // [1568][128]
  float* wt = ws + (size_t)WT_OFF;          // 5 x [128][128] transposed W's

  transposeW_kernel<<<dim3(16, 5), dim3(32, 8), 0, stream>>>(
      Wlk, Wrk, Wlv, Wrv, Wout, wt);
  proj4t_kernel<<<dim3(R_ / ROWS_PER_BLK, 4), 256, 0, stream>>>(
      key, value, wt, ws);
  attn_kernel<<<dim3(R_), 128, 0, stream>>>(ws, mask, xbuf);
  gemm_outt_kernel<<<dim3(R_ / ROWS_PER_BLK), 256, 0, stream>>>(
      xbuf, wt + (size_t)4 * D_ * D_, out);
}